// Round 4
// baseline (369.824 us; speedup 1.0000x reference)
//
#include <hip/hip_runtime.h>

#define E_TOTAL 32768
#define NJ 768

using bf16x8 = __attribute__((ext_vector_type(8))) short;
using f32x4  = __attribute__((ext_vector_type(4))) float;

__device__ __forceinline__ unsigned short f2bf(float x){
    unsigned u = __float_as_uint(x);
    u += 0x7fffu + ((u >> 16) & 1u);          // round-to-nearest-even
    return (unsigned short)(u >> 16);
}
__device__ __forceinline__ float bf2f(unsigned short h){
    return __uint_as_float((unsigned)h << 16);
}

// all-lanes sum within each 16-lane row: DPP row_ror 8/4/2/1 (VALU pipe only).
__device__ __forceinline__ float rowsum16(float x){
    x += __int_as_float(__builtin_amdgcn_update_dpp(0, __float_as_int(x), 0x128, 0xf, 0xf, false));
    x += __int_as_float(__builtin_amdgcn_update_dpp(0, __float_as_int(x), 0x124, 0xf, 0xf, false));
    x += __int_as_float(__builtin_amdgcn_update_dpp(0, __float_as_int(x), 0x122, 0xf, 0xf, false));
    x += __int_as_float(__builtin_amdgcn_update_dpp(0, __float_as_int(x), 0x121, 0xf, 0xf, false));
    return x;
}

// ---------------- prep: transpose + bf16(-split) all weights ----------------
// w3t[n*64+k]  = bf16(W3[k][n])                       (plain bf16, as before)
// w2t{h,l}[j*64+k] = split(W2[k][j])                  (K=64)
// w1t{h,l}[j*32+k] = split(W1[k][j]), k>=17 -> 0      (K=32 pad)
__global__ __launch_bounds__(256) void prep_weights(const float* __restrict__ W1,
        const float* __restrict__ W2, const float* __restrict__ W3,
        unsigned short* __restrict__ w3t, unsigned short* __restrict__ w2th,
        unsigned short* __restrict__ w2tl, unsigned short* __restrict__ w1th,
        unsigned short* __restrict__ w1tl){
    int t = blockIdx.x * 256 + threadIdx.x;
    if (t < 49152){
        int n = t >> 6, k = t & 63;
        w3t[t] = f2bf(W3[k * NJ + n]);
    } else if (t < 49152 + 4096){
        int u = t - 49152; int j = u >> 6, k = u & 63;
        float v = W2[k * 64 + j];
        unsigned short h = f2bf(v);
        w2th[u] = h; w2tl[u] = f2bf(v - bf2f(h));
    } else if (t < 49152 + 4096 + 2048){
        int u = t - 49152 - 4096; int j = u >> 5, k = u & 31;
        float v = (k < 17) ? W1[k * 64 + j] : 0.0f;
        unsigned short h = f2bf(v);
        w1th[u] = h; w1tl[u] = f2bf(v - bf2f(h));
    }
}

// ---------------- fused: MLP (MFMA split-bf16) + TP GEMM + einsum ----------------
// Each wave owns 16 edges end-to-end. No __syncthreads anywhere; no cross-wave
// sharing. Per-wave LDS 6912B: [sH 2304][union: sHa hi/lo 4608 | sR 3392] —
// aliasing safe via same-wave LDS program ordering (sHa reads precede sR writes).
__global__ __launch_bounds__(256, 2) void fused_kernel(const float* __restrict__ feat,
        const float* __restrict__ b1, const float* __restrict__ g1,
        const float* __restrict__ b2, const float* __restrict__ g2,
        const unsigned short* __restrict__ w1th, const unsigned short* __restrict__ w1tl,
        const unsigned short* __restrict__ w2th, const unsigned short* __restrict__ w2tl,
        const unsigned short* __restrict__ w3t, const float* __restrict__ b3,
        const float* __restrict__ basis, float* __restrict__ out){
    __shared__ __align__(16) char smem[4 * 6912];
    int tid = threadIdx.x;
    int wv = tid >> 6, l = tid & 63;
    char* wbase = smem + wv * 6912;
    unsigned short* sH   = (unsigned short*)wbase;            // [16][72] h2 bf16
    unsigned short* sHah = (unsigned short*)(wbase + 2304);   // [16][72] h1 hi
    unsigned short* sHal = (unsigned short*)(wbase + 4608);   // [16][72] h1 lo
    float*          sR   = (float*)(wbase + 2304);            // [16][53] (aliases sHa)

    int eb = (blockIdx.x * 4 + wv) * 16;       // this wave's 16 edges
    int c  = l & 15, kg = l >> 4;

    // ======== layer 1: 17->64, MFMA split-bf16 (fp32-accurate) ========
    // A-frag: row = c (edge), k = kg*8+i (K=32; k>=17 zeros)
    float fa[8];
    const float* fr = feat + (size_t)(eb + c) * 17;
    #pragma unroll
    for (int i = 0; i < 8; ++i) fa[i] = 0.0f;
    if (kg < 2){
        #pragma unroll
        for (int i = 0; i < 8; ++i) fa[i] = fr[kg * 8 + i];   // rows are 4B-aligned only
    } else if (kg == 2){
        fa[0] = fr[16];
    }
    bf16x8 Fh, Fl;
    #pragma unroll
    for (int i = 0; i < 8; ++i){
        unsigned short h = f2bf(fa[i]);
        Fh[i] = (short)h;
        Fl[i] = (short)f2bf(fa[i] - bf2f(h));
    }
    f32x4 x1[4];
    #pragma unroll
    for (int jt = 0; jt < 4; ++jt){
        int j = jt * 16 + c;
        bf16x8 Bh = *(const bf16x8*)(w1th + j * 32 + kg * 8);
        bf16x8 Bl = *(const bf16x8*)(w1tl + j * 32 + kg * 8);
        float bj = b1[j];
        f32x4 acc = {bj, bj, bj, bj};
        acc = __builtin_amdgcn_mfma_f32_16x16x32_bf16(Fh, Bh, acc, 0, 0, 0);
        acc = __builtin_amdgcn_mfma_f32_16x16x32_bf16(Fh, Bl, acc, 0, 0, 0);
        acc = __builtin_amdgcn_mfma_f32_16x16x32_bf16(Fl, Bh, acc, 0, 0, 0);
        #pragma unroll
        for (int r = 0; r < 4; ++r){            // silu
            float a = acc[r];
            x1[jt][r] = a / (1.0f + __expf(-a));
        }
    }
    // LN1: per edge (= D row, kg*4+r): reduce over jt in-reg + 16 lanes via DPP
    #pragma unroll
    for (int r = 0; r < 4; ++r){
        float s1 = x1[0][r] + x1[1][r] + x1[2][r] + x1[3][r];
        float s2 = x1[0][r]*x1[0][r] + x1[1][r]*x1[1][r]
                 + x1[2][r]*x1[2][r] + x1[3][r]*x1[3][r];
        s1 = rowsum16(s1);
        s2 = rowsum16(s2);
        float mu  = s1 * (1.0f / 64.0f);
        float var = s2 * (1.0f / 64.0f) - mu * mu;
        float rs  = rsqrtf(var + 1e-5f);
        #pragma unroll
        for (int jt = 0; jt < 4; ++jt){
            int j = jt * 16 + c;
            float h1 = (x1[jt][r] - mu) * rs * g1[j];
            unsigned short hh = f2bf(h1);
            sHah[(kg * 4 + r) * 72 + j] = hh;
            sHal[(kg * 4 + r) * 72 + j] = f2bf(h1 - bf2f(hh));
        }
    }

    // ======== layer 2: 64->64, MFMA split-bf16 ========
    bf16x8 Ah0 = *(const bf16x8*)(sHah + c * 72 + kg * 8);
    bf16x8 Ah1 = *(const bf16x8*)(sHah + c * 72 + 32 + kg * 8);
    bf16x8 Al0 = *(const bf16x8*)(sHal + c * 72 + kg * 8);
    bf16x8 Al1 = *(const bf16x8*)(sHal + c * 72 + 32 + kg * 8);
    f32x4 x2[4];
    #pragma unroll
    for (int jt = 0; jt < 4; ++jt){
        int j = jt * 16 + c;
        bf16x8 Bh0 = *(const bf16x8*)(w2th + j * 64 + kg * 8);
        bf16x8 Bh1 = *(const bf16x8*)(w2th + j * 64 + 32 + kg * 8);
        bf16x8 Bl0 = *(const bf16x8*)(w2tl + j * 64 + kg * 8);
        bf16x8 Bl1 = *(const bf16x8*)(w2tl + j * 64 + 32 + kg * 8);
        float bj = b2[j];
        f32x4 acc = {bj, bj, bj, bj};
        acc = __builtin_amdgcn_mfma_f32_16x16x32_bf16(Ah0, Bh0, acc, 0, 0, 0);
        acc = __builtin_amdgcn_mfma_f32_16x16x32_bf16(Ah1, Bh1, acc, 0, 0, 0);
        acc = __builtin_amdgcn_mfma_f32_16x16x32_bf16(Ah0, Bl0, acc, 0, 0, 0);
        acc = __builtin_amdgcn_mfma_f32_16x16x32_bf16(Ah1, Bl1, acc, 0, 0, 0);
        acc = __builtin_amdgcn_mfma_f32_16x16x32_bf16(Al0, Bh0, acc, 0, 0, 0);
        acc = __builtin_amdgcn_mfma_f32_16x16x32_bf16(Al1, Bh1, acc, 0, 0, 0);
        #pragma unroll
        for (int r = 0; r < 4; ++r){            // silu
            float a = acc[r];
            x2[jt][r] = a / (1.0f + __expf(-a));
        }
    }
    #pragma unroll
    for (int r = 0; r < 4; ++r){                // LN2 -> h2 bf16 -> sH
        float s1 = x2[0][r] + x2[1][r] + x2[2][r] + x2[3][r];
        float s2 = x2[0][r]*x2[0][r] + x2[1][r]*x2[1][r]
                 + x2[2][r]*x2[2][r] + x2[3][r]*x2[3][r];
        s1 = rowsum16(s1);
        s2 = rowsum16(s2);
        float mu  = s1 * (1.0f / 64.0f);
        float var = s2 * (1.0f / 64.0f) - mu * mu;
        float rs  = rsqrtf(var + 1e-5f);
        #pragma unroll
        for (int jt = 0; jt < 4; ++jt){
            int j = jt * 16 + c;
            sH[(kg * 4 + r) * 72 + j] = f2bf((x2[jt][r] - mu) * rs * g2[j]);
        }
    }

    // ======== TP: per-o 48-col GEMM -> wave-private sR -> einsum -> stores ========
    float bs[27];
    {
        const float* bp = basis + (size_t)(eb + (l >> 2)) * 27;
        #pragma unroll
        for (int z = 0; z < 27; ++z) bs[z] = bp[z];
    }
    bf16x8 a0 = *(const bf16x8*)(sH + c * 72 + kg * 8);        // k [0,32)
    bf16x8 a1 = *(const bf16x8*)(sH + c * 72 + 32 + kg * 8);   // k [32,64)
    float* outE = out + (size_t)(eb + (l >> 2)) * 2304;
    const float* Rrow = sR + (l >> 2) * 53;

    #pragma unroll 1
    for (int o = 0; o < 16; ++o){
        #pragma unroll
        for (int t = 0; t < 3; ++t){
            int n0 = o * 48 + t * 16;
            const unsigned short* wr = w3t + (size_t)(n0 + c) * 64;
            bf16x8 wb0 = *(const bf16x8*)(wr + kg * 8);
            bf16x8 wb1 = *(const bf16x8*)(wr + 32 + kg * 8);
            f32x4 acc = {0.f, 0.f, 0.f, 0.f};
            acc = __builtin_amdgcn_mfma_f32_16x16x32_bf16(a0, wb0, acc, 0, 0, 0);
            acc = __builtin_amdgcn_mfma_f32_16x16x32_bf16(a1, wb1, acc, 0, 0, 0);
            float bj = b3[n0 + c];
            #pragma unroll
            for (int r = 0; r < 4; ++r)
                sR[(kg * 4 + r) * 53 + t * 16 + c] = acc[r] + bj;  // D row=(l>>4)*4+r
        }
        // einsum for this o: lane handles edge l>>2, i = (l&3)*4 + ii
        #pragma unroll
        for (int ii = 0; ii < 4; ++ii){
            int i = (l & 3) * 4 + ii;
            float r0 = Rrow[i * 3 + 0];
            float r1 = Rrow[i * 3 + 1];
            float r2 = Rrow[i * 3 + 2];
            float* p = outE + o * 144 + i * 3;
            #pragma unroll
            for (int d = 0; d < 3; ++d){
                int z = d * 9;
                p[d * 48 + 0] = r0 * bs[z + 0] + r1 * bs[z + 1] + r2 * bs[z + 2];
                p[d * 48 + 1] = r0 * bs[z + 3] + r1 * bs[z + 4] + r2 * bs[z + 5];
                p[d * 48 + 2] = r0 * bs[z + 6] + r1 * bs[z + 7] + r2 * bs[z + 8];
            }
        }
    }
}

extern "C" void kernel_launch(void* const* d_in, const int* in_sizes, int n_in,
                              void* d_out, int out_size, void* d_ws, size_t ws_size,
                              hipStream_t stream) {
    const float* feat  = (const float*)d_in[0];
    const float* basis = (const float*)d_in[1];
    const float* W1 = (const float*)d_in[2];
    const float* b1 = (const float*)d_in[3];
    const float* g1 = (const float*)d_in[4];
    const float* W2 = (const float*)d_in[5];
    const float* b2 = (const float*)d_in[6];
    const float* g2 = (const float*)d_in[7];
    const float* W3 = (const float*)d_in[8];
    const float* b3 = (const float*)d_in[9];
    float* out = (float*)d_out;

    unsigned short* w3t  = (unsigned short*)d_ws;   // 49152 shorts
    unsigned short* w2th = w3t + 49152;             // 4096
    unsigned short* w2tl = w2th + 4096;             // 4096
    unsigned short* w1th = w2tl + 4096;             // 2048
    unsigned short* w1tl = w1th + 2048;             // 2048   (total 120 KB)

    prep_weights<<<216, 256, 0, stream>>>(W1, W2, W3, w3t, w2th, w2tl, w1th, w1tl);
    fused_kernel<<<E_TOTAL / 64, 256, 0, stream>>>(feat, b1, g1, b2, g2,
                                                   w1th, w1tl, w2th, w2tl,
                                                   w3t, b3, basis, out);
}